// Round 12
// baseline (194.055 us; speedup 1.0000x reference)
//
#include <hip/hip_runtime.h>

// 14-qubit state-vector sim, one workgroup per batch element, state in LDS.
// Wire w <-> bit (13-w). CNOT rings folded into scatter writes.
// R17: R14 restored verbatim (512 thr x 32 amps, 3 passes/layer, float2
//      consts + pk_fma_im — verified 127.9 us) + s_setprio(1/0) around the
//      gate-compute clusters (pure scheduler hint, no semantic effect).
//      Cross-lane gate merging is ABANDONED: R8/R9/R16 all failed ~0.05-0.07
//      with three independent implementations and paper-clean derivations —
//      some cross-lane-partner assumption is wrong on this stack. Ledger:
//      2x occupancy -> slower (4 passes); barrier removal -> -64%; spill
//      fix -> neutral; register diet -> +2%. Remaining gap to the 72us FLOP
//      floor is LDS latency + barrier drain at LDS-forced 2 waves/SIMD.

#define NW 14
#define NSTATE (1 << NW)                      // 16384
#define NTHREADS 512
#define STATE_SLOTS (NSTATE + ((NSTATE >> 6) << 1))   // 16896 float2

typedef float v2f __attribute__((ext_vector_type(2)));

__device__ __forceinline__ float2 cmul(float2 a, float2 b) {
    return make_float2(a.x * b.x - a.y * b.y, a.x * b.y + a.y * b.x);
}

// ---- VOP3P packed helpers (pk_fma_im verified on HW in R13/R14, absmax 0.0) ----
__device__ __forceinline__ v2f pk_mul_bl(v2f a, v2f b) {   // {a.lo*b.lo, a.hi*b.lo}
    v2f d; asm("v_pk_mul_f32 %0, %1, %2 op_sel:[0,0] op_sel_hi:[1,0]"
               : "=v"(d) : "v"(a), "v"(b)); return d;
}
__device__ __forceinline__ v2f pk_fma_bl(v2f a, v2f b, v2f c) { // {a.lo*b.lo+c.lo, a.hi*b.lo+c.hi}
    v2f d; asm("v_pk_fma_f32 %0, %1, %2, %3 op_sel:[0,0,0] op_sel_hi:[1,0,1]"
               : "=v"(d) : "v"(a), "v"(b), "v"(c)); return d;
}
// {c.lo - a.hi*b.hi, c.hi + a.lo*b.hi}: complex cross-term from U={re,im} directly
__device__ __forceinline__ v2f pk_fma_im(v2f a, v2f b, v2f c) {
    v2f d; asm("v_pk_fma_f32 %0, %1, %2, %3 op_sel:[1,1,0] op_sel_hi:[0,1,1] neg_lo:[0,1,0]"
               : "=v"(d) : "v"(a), "v"(b), "v"(c)); return d;
}

// ---- compile-time CNOT-ring constants ----
struct RingConsts { unsigned col[2][NW]; unsigned flow[2][32]; };
constexpr RingConsts make_rc() {
    RingConsts rc{};
    for (int ri = 0; ri < 2; ++ri) {
        for (int bb = 0; bb < NW; ++bb) {
            unsigned x = 1u << bb;
            for (int w = 0; w < NW; ++w) {
                int pc = 13 - w, pt = 13 - ((w + ri + 1) % NW);
                x ^= ((x >> pc) & 1u) << pt;
            }
            rc.col[ri][bb] = x;
        }
        for (int k = 0; k < 32; ++k) {
            unsigned x = 0;
            for (int b = 0; b < 5; ++b) if ((k >> b) & 1) x ^= rc.col[ri][b];
            rc.flow[ri][k] = x;
        }
    }
    return rc;
}
constexpr RingConsts RC = make_rc();

// Gate consts per wire W (4 float2 per gate: {u.re, u.im})
#define GSTAGE(W) \
    const float2 g0 = G4[(W)*4+0], g1 = G4[(W)*4+1], \
                 g2 = G4[(W)*4+2], g3 = G4[(W)*4+3]; \
    const v2f U00 = (v2f){g0.x,g0.y}, U01 = (v2f){g1.x,g1.y}; \
    const v2f U10 = (v2f){g2.x,g2.y}, U11 = (v2f){g3.x,g3.y};

#define CBFA(X, Y) { \
    v2f n0 = pk_mul_bl(X, U00); n0 = pk_fma_im(X, U00, n0); \
    n0 = pk_fma_bl(Y, U01, n0); n0 = pk_fma_im(Y, U01, n0); \
    v2f n1 = pk_mul_bl(X, U10); n1 = pk_fma_im(X, U10, n1); \
    n1 = pk_fma_bl(Y, U11, n1); n1 = pk_fma_im(Y, U11, n1); \
    X = n0; Y = n1; }

#define FE32(M) M(0) M(1) M(2) M(3) M(4) M(5) M(6) M(7) M(8) M(9) M(10) M(11) \
    M(12) M(13) M(14) M(15) M(16) M(17) M(18) M(19) M(20) M(21) M(22) M(23) \
    M(24) M(25) M(26) M(27) M(28) M(29) M(30) M(31)

// butterfly pair lists per k-bit
#define P4(M) M(A0,A16) M(A1,A17) M(A2,A18) M(A3,A19) M(A4,A20) M(A5,A21) M(A6,A22) M(A7,A23) \
              M(A8,A24) M(A9,A25) M(A10,A26) M(A11,A27) M(A12,A28) M(A13,A29) M(A14,A30) M(A15,A31)
#define P3(M) M(A0,A8) M(A1,A9) M(A2,A10) M(A3,A11) M(A4,A12) M(A5,A13) M(A6,A14) M(A7,A15) \
              M(A16,A24) M(A17,A25) M(A18,A26) M(A19,A27) M(A20,A28) M(A21,A29) M(A22,A30) M(A23,A31)
#define P2(M) M(A0,A4) M(A1,A5) M(A2,A6) M(A3,A7) M(A8,A12) M(A9,A13) M(A10,A14) M(A11,A15) \
              M(A16,A20) M(A17,A21) M(A18,A22) M(A19,A23) M(A24,A28) M(A25,A29) M(A26,A30) M(A27,A31)
#define P1(M) M(A0,A2) M(A1,A3) M(A4,A6) M(A5,A7) M(A8,A10) M(A9,A11) M(A12,A14) M(A13,A15) \
              M(A16,A18) M(A17,A19) M(A20,A22) M(A21,A23) M(A24,A26) M(A25,A27) M(A28,A30) M(A29,A31)
#define P0(M) M(A0,A1) M(A2,A3) M(A4,A5) M(A6,A7) M(A8,A9) M(A10,A11) M(A12,A13) M(A14,A15) \
              M(A16,A17) M(A18,A19) M(A20,A21) M(A22,A23) M(A24,A25) M(A26,A27) M(A28,A29) M(A30,A31)

// 5 gates on k-bits 4..0 = wires W0..W0+4; 32 amps/thread, affine padded addrs.
template<int LO, int W0>
__device__ __forceinline__ void rot_pass5(float2* st_, const float2* G4, int t)
{
    const int base = ((t >> LO) << (LO + 5)) | (t & ((1 << LO) - 1));
    float2* pA = st_ + (base + ((base >> 6) << 1));
#define OFF(k) ((((k)) << LO) + (((((k)) << LO) >> 6) << 1))
    float2* pB = pA + OFF(16);
#define ADR(k) ((k) < 16 ? (pA + OFF(k)) : (pB + OFF((k) - 16)))
#define DECL(k) v2f A##k;
    FE32(DECL)
#undef DECL
#define LD(k) A##k = *(const v2f*)ADR(k);
    FE32(LD)
#undef LD
    __builtin_amdgcn_s_setprio(1);
    { GSTAGE(W0+0) P4(CBFA) }
    { GSTAGE(W0+1) P3(CBFA) }
    { GSTAGE(W0+2) P2(CBFA) }
    { GSTAGE(W0+3) P1(CBFA) }
    { GSTAGE(W0+4) P0(CBFA) }
    __builtin_amdgcn_s_setprio(0);
#define ST(k) *(v2f*)ADR(k) = A##k;
    FE32(ST)
#undef ST
#undef ADR
#undef OFF
}

// contiguous 32-amp load (b128) + gates on wires 10..13 (k-bits 3..0)
#define LOW_LOAD_GATES \
    const float4* lp = (const float4*)(st_ + (32 * t + ((t >> 1) << 1))); \
    const float4 q0 = lp[0],  q1 = lp[1],  q2 = lp[2],  q3 = lp[3], \
                 q4 = lp[4],  q5 = lp[5],  q6 = lp[6],  q7 = lp[7], \
                 q8 = lp[8],  q9 = lp[9],  q10 = lp[10], q11 = lp[11], \
                 q12 = lp[12], q13 = lp[13], q14 = lp[14], q15 = lp[15]; \
    v2f A0  = (v2f){q0.x,q0.y},  A1  = (v2f){q0.z,q0.w}, \
        A2  = (v2f){q1.x,q1.y},  A3  = (v2f){q1.z,q1.w}, \
        A4  = (v2f){q2.x,q2.y},  A5  = (v2f){q2.z,q2.w}, \
        A6  = (v2f){q3.x,q3.y},  A7  = (v2f){q3.z,q3.w}, \
        A8  = (v2f){q4.x,q4.y},  A9  = (v2f){q4.z,q4.w}, \
        A10 = (v2f){q5.x,q5.y},  A11 = (v2f){q5.z,q5.w}, \
        A12 = (v2f){q6.x,q6.y},  A13 = (v2f){q6.z,q6.w}, \
        A14 = (v2f){q7.x,q7.y},  A15 = (v2f){q7.z,q7.w}, \
        A16 = (v2f){q8.x,q8.y},  A17 = (v2f){q8.z,q8.w}, \
        A18 = (v2f){q9.x,q9.y},  A19 = (v2f){q9.z,q9.w}, \
        A20 = (v2f){q10.x,q10.y}, A21 = (v2f){q10.z,q10.w}, \
        A22 = (v2f){q11.x,q11.y}, A23 = (v2f){q11.z,q11.w}, \
        A24 = (v2f){q12.x,q12.y}, A25 = (v2f){q12.z,q12.w}, \
        A26 = (v2f){q13.x,q13.y}, A27 = (v2f){q13.z,q13.w}, \
        A28 = (v2f){q14.x,q14.y}, A29 = (v2f){q14.z,q14.w}, \
        A30 = (v2f){q15.x,q15.y}, A31 = (v2f){q15.z,q15.w}; \
    __builtin_amdgcn_s_setprio(1); \
    { GSTAGE(10) P3(CBFA) } \
    { GSTAGE(11) P2(CBFA) } \
    { GSTAGE(12) P1(CBFA) } \
    { GSTAGE(13) P0(CBFA) } \
    __builtin_amdgcn_s_setprio(0);

// wires 10..13 + ring permutation folded into scatter (full XOR + SLOT)
template<int RI>
__device__ __forceinline__ void rot_low_ring5(float2* st_, const float2* G4, int t,
                                              const unsigned* lA, const unsigned* lB)
{
    LOW_LOAD_GATES
    const unsigned fb = lA[t & 31] ^ lB[t >> 5];      // image of (t<<5), any bits
    __syncthreads();                                  // all reads done before scatter
#define SC(k) { const unsigned ix = fb ^ RC.flow[RI][(k)]; \
    st_[ix + ((ix >> 6) << 1)] = make_float2(A##k.x, A##k.y); }
    FE32(SC)
#undef SC
}

// final layer: wires 10..13 + ring(RI=1) + <Z> measurement, no writeback
__device__ __forceinline__ float rot_low_meas5(float2* st_, const float2* G4, int t,
                                               const unsigned* lA, const unsigned* lB,
                                               const float* s_hw)
{
    LOW_LOAD_GATES
    const unsigned fb = lA[t & 31] ^ lB[t >> 5];
#define SGV(b) ((((fb >> b) & 1u) ? -1.f : 1.f) * s_hw[13 - (b)])
    const float sg0 = SGV(0),  sg1 = SGV(1),  sg2 = SGV(2),  sg3 = SGV(3),
                sg4 = SGV(4),  sg5 = SGV(5),  sg6 = SGV(6),  sg7 = SGV(7),
                sg8 = SGV(8),  sg9 = SGV(9),  sg10 = SGV(10), sg11 = SGV(11),
                sg12 = SGV(12), sg13 = SGV(13);
#undef SGV
    const float chiS = ((sg0 + sg1) + (sg2 + sg3)) + ((sg4 + sg5) + (sg6 + sg7))
                     + ((sg8 + sg9) + (sg10 + sg11)) + (sg12 + sg13);
#define SUBSUM(F) ( ((F)&1u?sg0:0.f) + ((F)&2u?sg1:0.f) + ((F)&4u?sg2:0.f) + ((F)&8u?sg3:0.f) \
                  + ((F)&16u?sg4:0.f) + ((F)&32u?sg5:0.f) + ((F)&64u?sg6:0.f) + ((F)&128u?sg7:0.f) \
                  + ((F)&256u?sg8:0.f) + ((F)&512u?sg9:0.f) + ((F)&1024u?sg10:0.f) + ((F)&2048u?sg11:0.f) \
                  + ((F)&4096u?sg12:0.f) + ((F)&8192u?sg13:0.f) )
    float acc = 0.f;
#define MEASK(k) { const float p2 = fmaf(A##k.x, A##k.x, A##k.y * A##k.y); \
    acc = fmaf(p2, chiS - 2.f * SUBSUM(RC.flow[1][(k)]), acc); }
    FE32(MEASK)
#undef MEASK
#undef SUBSUM
    return acc;
}

__global__ __launch_bounds__(NTHREADS, 2)
void qsim(const float* __restrict__ sb, const float* __restrict__ pr,
          const float* __restrict__ hw, const float* __restrict__ hb,
          float* __restrict__ out)
{
    __shared__ __align__(16) float2 st[STATE_SLOTS];   // 135,168 B
    __shared__ __align__(16) float2 rotc[2][NW * 4];   // gate consts {re, im}
    __shared__ unsigned lutA[2][32], lutB[2][16];      // fb LUTs: i bits 5..9 / 10..13
    __shared__ float2 low_tab[32];                     // layer0 product over wires 9..13
    __shared__ float s_hw[NW];
    __shared__ float s_red[NTHREADS / 64];
    __shared__ unsigned s_bmask;

    const int bid = blockIdx.x;
    const int t = threadIdx.x;

    // ---- setup ----
    if (t < 28) {
        int l = t / NW, w = t % NW;
        const float* p = pr + bid * 84 + l * 42 + w * 3;
        float phi = p[0], th = p[1], om = p[2];
        float s, cth;  __sincosf(0.5f * th, &s, &cth);
        float sa, ca, sd, cd;
        __sincosf(0.5f * (phi + om), &sa, &ca);
        __sincosf(0.5f * (phi - om), &sd, &cd);
        rotc[l][w*4+0] = make_float2(ca * cth, -sa * cth);   // u00
        rotc[l][w*4+1] = make_float2(-cd * s,  -sd * s);     // u01
        rotc[l][w*4+2] = make_float2(cd * s,   -sd * s);     // u10
        rotc[l][w*4+3] = make_float2(ca * cth,  sa * cth);   // u11
    }
    if (t >= 64 && t < 128) {                   // lutA: i bits 5..9 from t bits 0..4
        int j = t - 64, ri = j >> 5, m = j & 31;
        unsigned x = 0;
        for (int b = 0; b < 5; ++b) if ((m >> b) & 1) x ^= RC.col[ri][5 + b];
        lutA[ri][m] = x;
    }
    if (t >= 128 && t < 160) {                  // lutB: i bits 10..13 from t bits 5..8
        int j = t - 128, ri = j >> 4, m = j & 15;
        unsigned x = 0;
        for (int b = 0; b < 4; ++b) if ((m >> b) & 1) x ^= RC.col[ri][10 + b];
        lutB[ri][m] = x;
    }
    if (t >= 160 && t < 174) s_hw[t - 160] = hw[t - 160];
    if (t == 192) {
        const float* row = sb + (size_t)bid * (NSTATE * 2);
        unsigned m = 0;
        for (int w = 0; w < NW; ++w) m |= (row[w] < 0.0f ? 1u : 0u) << (13 - w);
        s_bmask = m;
    }
    __syncthreads();
    if (t < 32) {                               // low_tab[k]: wires 9..13 (i bits 4..0)
        const unsigned bm = s_bmask;
        float2 v = make_float2(1.f, 0.f);
#pragma unroll
        for (int b = 0; b < 5; ++b) {
            int w = 13 - b, kb = (t >> b) & 1, cb = (bm >> b) & 1;
            float2 e = rotc[0][w*4 + kb*2 + cb];
            v = cmul(v, e);
        }
        low_tab[t] = v;
    }
    __syncthreads();

    // ---- init: layer 0 on |bm> (product state), ring r=1 folded ----
    {
        const unsigned bm = s_bmask;
        float2 ph = make_float2(1.f, 0.f);
#pragma unroll
        for (int w = 0; w < 9; ++w) {           // wires 0..8 from t bits 8..0
            int v = (t >> (8 - w)) & 1;
            int bw = (bm >> (13 - w)) & 1;
            float2 e = rotc[0][w*4 + v*2 + bw];
            ph = cmul(ph, e);
        }
        const unsigned fb = lutA[0][t & 31] ^ lutB[0][t >> 5];
#define INITK(k) { const unsigned ix = fb ^ RC.flow[0][(k)]; \
    const float2 lt = low_tab[(k)]; \
    st[ix + ((ix >> 6) << 1)] = cmul(ph, lt); }
        FE32(INITK)
#undef INITK
    }
    __syncthreads();

    // ---- reps 0..3: layers (1,0,1,0), 3 passes each, trailing ring folded ----
#pragma unroll 1
    for (int rep = 0; rep < 4; ++rep) {
        const int l = (rep & 1) ? 0 : 1;
        const float2* G4 = &rotc[l][0];
        rot_pass5<9, 0>(st, G4, t); __syncthreads();   // wires 0..4
        rot_pass5<4, 5>(st, G4, t); __syncthreads();   // wires 5..9
        if (l) rot_low_ring5<1>(st, G4, t, lutA[1], lutB[1]);
        else   rot_low_ring5<0>(st, G4, t, lutA[0], lutB[0]);
        __syncthreads();
    }
    // ---- final: layer 1, ring r=2 + measurement folded ----
    rot_pass5<9, 0>(st, &rotc[1][0], t); __syncthreads();
    rot_pass5<4, 5>(st, &rotc[1][0], t); __syncthreads();
    float acc = rot_low_meas5(st, &rotc[1][0], t, lutA[1], lutB[1], s_hw);

    for (int off = 32; off > 0; off >>= 1) acc += __shfl_down(acc, off);
    if ((t & 63) == 0) s_red[t >> 6] = acc;
    __syncthreads();
    if (t == 0) {
        float tot = 0.f;
#pragma unroll
        for (int i = 0; i < NTHREADS / 64; ++i) tot += s_red[i];
        out[bid] = tot + hb[0];
    }
}

extern "C" void kernel_launch(void* const* d_in, const int* in_sizes, int n_in,
                              void* d_out, int out_size, void* d_ws, size_t ws_size,
                              hipStream_t stream)
{
    const float* sb = (const float*)d_in[0];   // state_batch (B, 2^14, 2) f32
    const float* pr = (const float*)d_in[1];   // params (B, 84) f32
    const float* hw = (const float*)d_in[2];   // head_w (1, 14) f32
    const float* hb = (const float*)d_in[3];   // head_b (1,) f32
    float* out = (float*)d_out;                // (B,) f32
    const int B = in_sizes[1] / 84;            // 512
    qsim<<<B, NTHREADS, 0, stream>>>(sb, pr, hw, hb, out);
}